// Round 27
// baseline (117.114 us; speedup 1.0000x reference)
//
#include <hip/hip_runtime.h>
#include <hip/hip_bf16.h>
#include <math.h>

// GateFusion via bf16 MFMA (16x16x32). PRODUCER-CONSUMER wave specialization
// (the one untried structure; docs name it the path past barrier-drain).
// 256 persistent blocks (1/CU), 8 waves = 4 pairs: producer waves stream x
// tiles into double-buffered LDS (asm burst -> vmcnt(0) -> ds_write, all
// adjacent = r15-proven-safe; loads drain in the PRODUCER's stream while
// CONSUMER waves compute -> overlap by construction, immune to the regalloc
// pathologies r9/r21/r24/r25). Consumers run the r23-proven compute:
// all-LDS weight frags, LN gate, phase-2, LDS-transpose + 512B NT stores.
// One __syncthreads per round; loop carries only scalars (no r6/r12 hoist).
// out = g * (x_d@W_d) + (1-g) * (x_c@W_c),
// g = sigmoid( relu(LN(concat@Wg1)) @ Wg2 ),  per row.
//
// d_ws: fragment-linear bf16 weights; lane l of frag holds B[k(l,j)][n],
//   n = nt*16 + (l&15),  k(l,j) = ks*32 + (j>>2)*16 + (l>>4)*4 + (j&3)
// (coalesced-load k-map; identical permutation in A and B operands cancels).

namespace {

typedef __attribute__((ext_vector_type(8))) short short8;
typedef __attribute__((ext_vector_type(4))) float f32x4;

constexpr int CD = 64, CC = 96, CH = 64, CF = 128;
constexpr int NFG1 = 20;
constexpr int NFCB = 40;
constexpr int NFRAG = NFG1 + NFCB;            // 60 frags = 61440 B
constexpr int WCH_ALL = NFRAG * 512 * 2 / 16; // 3840 x 16B

__device__ inline short bf16_of(float f) {
  __hip_bfloat16 h = __float2bfloat16(f);
  return *reinterpret_cast<short*>(&h);
}

__global__ void convert_weights(const float* __restrict__ Wd,
                                const float* __restrict__ Wc,
                                const float* __restrict__ Wg1,
                                short* __restrict__ ws) {
  const int t = blockIdx.x * 256 + threadIdx.x;
  if (t >= 64 * NFRAG) return;
  const int frag = t >> 6, l = t & 63;
  const int cidx = l & 15, kb = l >> 4;
  float v[8];
  if (frag < NFG1) {
    const int ks = frag >> 2, nt = frag & 3;
    const int n = nt * 16 + cidx;
    #pragma unroll
    for (int j = 0; j < 8; ++j) {
      const int k = ks * 32 + (j >> 2) * 16 + kb * 4 + (j & 3);
      v[j] = Wg1[k * CH + n];
    }
  } else {
    const int f2 = frag - NFG1;
    const int ks = f2 >> 3, nt = f2 & 7;
    const int n = nt * 16 + cidx;
    #pragma unroll
    for (int j = 0; j < 8; ++j) {
      const int k = ks * 32 + (j >> 2) * 16 + kb * 4 + (j & 3);
      v[j] = (k < CD) ? Wd[k * CF + n] : Wc[(k - CD) * CF + n];
    }
  }
  short8 o;
  #pragma unroll
  for (int j = 0; j < 8; ++j) o[j] = bf16_of(v[j]);
  *reinterpret_cast<short8*>(ws + frag * 512 + l * 8) = o;
}

// 10 global_load_dwordx4 as one immovable block (4 x_d + 6 x_c segments).
#define BURST(p0,p1,p2,p3,p4,p5,p6,p7,p8,p9, rdp, rcp)                \
  asm volatile(                                                        \
      "global_load_dwordx4 %0, %[ad], off\n\t"                         \
      "global_load_dwordx4 %1, %[ad], off offset:64\n\t"               \
      "global_load_dwordx4 %2, %[ad], off offset:128\n\t"              \
      "global_load_dwordx4 %3, %[ad], off offset:192\n\t"              \
      "global_load_dwordx4 %4, %[ac], off\n\t"                         \
      "global_load_dwordx4 %5, %[ac], off offset:64\n\t"               \
      "global_load_dwordx4 %6, %[ac], off offset:128\n\t"              \
      "global_load_dwordx4 %7, %[ac], off offset:192\n\t"              \
      "global_load_dwordx4 %8, %[ac], off offset:256\n\t"              \
      "global_load_dwordx4 %9, %[ac], off offset:320"                  \
      : "=&v"(p0), "=&v"(p1), "=&v"(p2), "=&v"(p3), "=&v"(p4),         \
        "=&v"(p5), "=&v"(p6), "=&v"(p7), "=&v"(p8), "=&v"(p9)          \
      : [ad] "v"(rdp), [ac] "v"(rcp)                                   \
      : "memory")

#define WAIT0(p0,p1,p2,p3,p4,p5,p6,p7,p8,p9)                           \
  asm volatile("s_waitcnt vmcnt(0)"                                    \
      : "+v"(p0), "+v"(p1), "+v"(p2), "+v"(p3), "+v"(p4),              \
        "+v"(p5), "+v"(p6), "+v"(p7), "+v"(p8), "+v"(p9)               \
      :: "memory")

__global__ __launch_bounds__(512, 1)
void gate_fusion_mfma(const float* __restrict__ xd,
                      const float* __restrict__ xc,
                      const float* __restrict__ gma,
                      const float* __restrict__ bta,
                      const float* __restrict__ Wg2,
                      const short* __restrict__ wf,
                      float* __restrict__ out,
                      int nTiles, int T) {
  __shared__ short wlds[NFRAG * 512];    // 61440 B: all weight frags
  __shared__ f32x4 xbuf[2][4][640];      // 81920 B: double-buffered x tiles
  __shared__ float tr[4][4][136];        //  8704 B: consumer epilogue scratch

  const int tid  = threadIdx.x;
  const int lane = tid & 63;
  const int wv   = tid >> 6;                 // 0..7
  const int cidx = lane & 15;
  const int kb   = lane >> 4;
  const bool producer = (wv >= 4);
  const int  pair     = producer ? (wv - 4) : wv;   // 0..3
  const int  tbase    = blockIdx.x * T * 4;         // block's first tile

  // ---- stage all 60 weight frags (61440 B) into LDS (all 8 waves)
  {
    #pragma unroll
    for (int it = 0; it < 8; ++it) {
      const int c = tid + it * 512;
      if (it < 7 || c < WCH_ALL) {
        short8 v = *reinterpret_cast<const short8*>(wf + (size_t)c * 8);
        *reinterpret_cast<short8*>(&wlds[c * 8]) = v;
      }
    }
  }

  // producer: load one tile (clamped) and write into buffer bsel
  auto produce = [&](int t, int bsel) {
    const int tc = (t < nTiles) ? t : (nTiles - 1);
    const float* rdp = xd + ((size_t)tc * 16 + cidx) * CD + kb * 4;
    const float* rcp = xc + ((size_t)tc * 16 + cidx) * CC + kb * 4;
    f32x4 b0,b1,b2,b3,b4,b5,b6,b7,b8,b9;
    BURST(b0,b1,b2,b3,b4,b5,b6,b7,b8,b9, rdp, rcp);
    WAIT0(b0,b1,b2,b3,b4,b5,b6,b7,b8,b9);
    __builtin_amdgcn_sched_barrier(0);
    f32x4* dst = &xbuf[bsel][pair][0];
    dst[0 * 64 + lane] = b0;  dst[1 * 64 + lane] = b1;
    dst[2 * 64 + lane] = b2;  dst[3 * 64 + lane] = b3;
    dst[4 * 64 + lane] = b4;  dst[5 * 64 + lane] = b5;
    dst[6 * 64 + lane] = b6;  dst[7 * 64 + lane] = b7;
    dst[8 * 64 + lane] = b8;  dst[9 * 64 + lane] = b9;
  };

  // consumer constants
  float gmv[4], btv[4], w2v[4];
  if (!producer) {
    #pragma unroll
    for (int nt = 0; nt < 4; ++nt) {
      const int c = nt * 16 + cidx;
      gmv[nt] = gma[c]; btv[nt] = bta[c]; w2v[nt] = Wg2[c];
    }
  }

  const f32x4 vzero = {0.f, 0.f, 0.f, 0.f};

  // consumer: full r23 compute on tile t from buffer bsel
  auto consume = [&](int t, int bsel) {
    if (t >= nTiles) return;                 // wave-uniform
    const int r0 = t * 16;
    const f32x4* src = &xbuf[bsel][pair][0];

    short8 xf[5];
    #pragma unroll
    for (int ks = 0; ks < 5; ++ks) {
      const f32x4 lo = src[(2 * ks) * 64 + lane];
      const f32x4 hi = src[(2 * ks + 1) * 64 + lane];
      short8 f;
      #pragma unroll
      for (int j = 0; j < 4; ++j) { f[j] = bf16_of(lo[j]); f[4 + j] = bf16_of(hi[j]); }
      xf[ks] = f;
    }

    // phase 1: h = x @ Wg1
    f32x4 acc1[4];
    #pragma unroll
    for (int nt = 0; nt < 4; ++nt) acc1[nt] = vzero;
    #pragma unroll
    for (int ks = 0; ks < 5; ++ks) {
      short8 bg[4];
      #pragma unroll
      for (int nt = 0; nt < 4; ++nt)
        bg[nt] = *reinterpret_cast<const short8*>(
            &wlds[(ks * 4 + nt) * 512 + lane * 8]);
      #pragma unroll
      for (int nt = 0; nt < 4; ++nt)
        acc1[nt] = __builtin_amdgcn_mfma_f32_16x16x32_bf16(
            xf[ks], bg[nt], acc1[nt], 0, 0, 0);
    }

    // LayerNorm + relu + dot(Wg2) + sigmoid
    float gate[4];
    {
      float s[4], q[4];
      #pragma unroll
      for (int r = 0; r < 4; ++r) {
        s[r] = 0.f; q[r] = 0.f;
        #pragma unroll
        for (int nt = 0; nt < 4; ++nt) {
          const float c = acc1[nt][r];
          s[r] += c; q[r] += c * c;
        }
      }
      #pragma unroll
      for (int m = 1; m < 16; m <<= 1)
        #pragma unroll
        for (int r = 0; r < 4; ++r) {
          s[r] += __shfl_xor(s[r], m, 64);
          q[r] += __shfl_xor(q[r], m, 64);
        }
      float p[4];
      #pragma unroll
      for (int r = 0; r < 4; ++r) {
        const float mu  = s[r] * (1.f / CH);
        const float var = q[r] * (1.f / CH) - mu * mu;
        const float rsd = rsqrtf(var + 1e-5f);
        float pp = 0.f;
        #pragma unroll
        for (int nt = 0; nt < 4; ++nt) {
          const float h = fmaxf((acc1[nt][r] - mu) * rsd * gmv[nt] + btv[nt], 0.f);
          pp += h * w2v[nt];
        }
        p[r] = pp;
      }
      #pragma unroll
      for (int m = 1; m < 16; m <<= 1)
        #pragma unroll
        for (int r = 0; r < 4; ++r) p[r] += __shfl_xor(p[r], m, 64);
      #pragma unroll
      for (int r = 0; r < 4; ++r) gate[r] = 1.f / (1.f + expf(-p[r]));
    }

    // phase 2
    f32x4 o[4][2];
    #pragma unroll
    for (int q = 0; q < 4; ++q) {
      f32x4 aD[2], aC[2];
      #pragma unroll
      for (int nt = 0; nt < 2; ++nt) { aD[nt] = vzero; aC[nt] = vzero; }
      #pragma unroll
      for (int ks = 0; ks < 5; ++ks) {
        short8 bg[2];
        #pragma unroll
        for (int nt = 0; nt < 2; ++nt)
          bg[nt] = *reinterpret_cast<const short8*>(
              &wlds[(NFG1 + ks * 8 + q * 2 + nt) * 512 + lane * 8]);
        if (ks < 2) {
          #pragma unroll
          for (int nt = 0; nt < 2; ++nt)
            aD[nt] = __builtin_amdgcn_mfma_f32_16x16x32_bf16(
                xf[ks], bg[nt], aD[nt], 0, 0, 0);
        } else {
          #pragma unroll
          for (int nt = 0; nt < 2; ++nt)
            aC[nt] = __builtin_amdgcn_mfma_f32_16x16x32_bf16(
                xf[ks], bg[nt], aC[nt], 0, 0, 0);
        }
      }
      #pragma unroll
      for (int nt = 0; nt < 2; ++nt)
        #pragma unroll
        for (int r = 0; r < 4; ++r)
          o[q][nt][r] = fmaf(gate[r], aD[nt][r] - aC[nt][r], aC[nt][r]);
    }

    // transpose epilogue + 512B-contiguous NT stores (single use per wave
    // per round; per-pair scratch)
    {
      float (*trw)[136] = tr[pair];
      #pragma unroll
      for (int r = 0; r < 4; ++r) {
        #pragma unroll
        for (int q = 0; q < 4; ++q)
          #pragma unroll
          for (int nt = 0; nt < 2; ++nt)
            trw[kb][(q * 2 + nt) * 16 + cidx] = o[q][nt][r];
        #pragma unroll
        for (int i = 0; i < 2; ++i) {
          const int ri = i * 2 + (lane >> 5);
          const f32x4 v = *reinterpret_cast<const f32x4*>(
              &trw[ri][(lane & 31) * 4]);
          float* dst = &out[((size_t)r0 + ri * 4 + r) * CF + (lane & 31) * 4];
          asm volatile("global_store_dwordx4 %0, %1, off nt"
                       :: "v"(dst), "v"(v) : "memory");
        }
      }
    }
  };

  // ---- prologue: producers fill buffer 0 for round 0
  if (producer) produce(tbase + 0 * 4 + pair, 0);
  __syncthreads();   // weights + round-0 x ready

  // ---- round loop: producers fill buf[(r+1)&1] while consumers eat buf[r&1]
  for (int r = 0; r < T; ++r) {
    if (producer) {
      if (r + 1 < T) produce(tbase + (r + 1) * 4 + pair, (r + 1) & 1);
    } else {
      consume(tbase + r * 4 + pair, r & 1);
    }
    __syncthreads();
  }
}

}  // namespace

extern "C" void kernel_launch(void* const* d_in, const int* in_sizes, int n_in,
                              void* d_out, int out_size, void* d_ws, size_t ws_size,
                              hipStream_t stream) {
  const float* xd  = (const float*)d_in[0];
  const float* xc  = (const float*)d_in[1];
  const float* Wd  = (const float*)d_in[2];
  const float* Wc  = (const float*)d_in[3];
  const float* Wg1 = (const float*)d_in[4];
  const float* gma = (const float*)d_in[5];
  const float* bta = (const float*)d_in[6];
  const float* Wg2 = (const float*)d_in[7];
  float* out = (float*)d_out;
  short* ws  = (short*)d_ws;   // needs 60 KB

  const int N = in_sizes[0] / CD;
  const int nTiles = N / 16;             // 31250

  convert_weights<<<dim3(15), dim3(256), 0, stream>>>(Wd, Wc, Wg1, ws);

  const int nblk = 256;                  // 1 block/CU (LDS-forced)
  const int T = (nTiles + nblk * 4 - 1) / (nblk * 4);   // rounds per block
  gate_fusion_mfma<<<dim3(nblk), dim3(512), 0, stream>>>(
      xd, xc, gma, bta, Wg2, ws, out, nTiles, T);
}

// Round 29
// 114.378 us; speedup vs baseline: 1.0239x; 1.0239x over previous
//
#include <hip/hip_runtime.h>
#include <hip/hip_bf16.h>
#include <math.h>

// GateFusion via bf16 MFMA (16x16x32). TERMINAL configuration (= r23/r26,
// verified twice at 114.3-115.0us): one-shot 8-wave blocks, ALL 60 weight
// frags staged in LDS (no exposed L2 latency on the MFMA critical path),
// coalesced x-load burst, LDS-transpose epilogue + 512B-contiguous NT
// stores (NT needs >=512B contiguity: r20), exact HBM traffic
// (FETCH 156.5MB / WRITE 250MB bit-exact).
// Closed lines (session ledger): cross-tile load/compute overlap is
// unavailable on this toolchain -- source prefetch spills (r3/4/6), DMA
// over-fetches (r10), asm pipelines barrier-drained (r17) or vmcnt-unsound
// (r21), and all high-pressure dual-buffer variants corrupt deterministically
// with absmax 1.578125 (r21/r24/r28; suspected pressure-triggered miscompile
// around "memory"-clobbered asm). Producer-consumer split is correct but
// latency-starved at 4C (r27=117us) and corrupts at 8C/12w (r28).
// out = g * (x_d@W_d) + (1-g) * (x_c@W_c),
// g = sigmoid( relu(LN(concat@Wg1)) @ Wg2 ),  per row.
//
// d_ws: fragment-linear bf16 weights; lane l of frag holds B[k(l,j)][n],
//   n = nt*16 + (l&15),  k(l,j) = ks*32 + (j>>2)*16 + (l>>4)*4 + (j&3)
// (coalesced-load k-map; identical permutation in A and B operands cancels).

namespace {

typedef __attribute__((ext_vector_type(8))) short short8;
typedef __attribute__((ext_vector_type(4))) float f32x4;

constexpr int CD = 64, CC = 96, CH = 64, CF = 128;
constexpr int NFG1 = 20;   // gate-weight frags
constexpr int NFCB = 40;   // output-weight frags
constexpr int NFRAG = NFG1 + NFCB;            // 60 frags = 61440 B
constexpr int WCH_ALL = NFRAG * 512 * 2 / 16; // 3840 x 16B

__device__ inline short bf16_of(float f) {
  __hip_bfloat16 h = __float2bfloat16(f);
  return *reinterpret_cast<short*>(&h);
}

__global__ void convert_weights(const float* __restrict__ Wd,
                                const float* __restrict__ Wc,
                                const float* __restrict__ Wg1,
                                short* __restrict__ ws) {
  const int t = blockIdx.x * 256 + threadIdx.x;
  if (t >= 64 * NFRAG) return;
  const int frag = t >> 6, l = t & 63;
  const int cidx = l & 15, kb = l >> 4;
  float v[8];
  if (frag < NFG1) {
    const int ks = frag >> 2, nt = frag & 3;
    const int n = nt * 16 + cidx;
    #pragma unroll
    for (int j = 0; j < 8; ++j) {
      const int k = ks * 32 + (j >> 2) * 16 + kb * 4 + (j & 3);
      v[j] = Wg1[k * CH + n];
    }
  } else {
    const int f2 = frag - NFG1;
    const int ks = f2 >> 3, nt = f2 & 7;
    const int n = nt * 16 + cidx;
    #pragma unroll
    for (int j = 0; j < 8; ++j) {
      const int k = ks * 32 + (j >> 2) * 16 + kb * 4 + (j & 3);
      v[j] = (k < CD) ? Wd[k * CF + n] : Wc[(k - CD) * CF + n];
    }
  }
  short8 o;
  #pragma unroll
  for (int j = 0; j < 8; ++j) o[j] = bf16_of(v[j]);
  *reinterpret_cast<short8*>(ws + frag * 512 + l * 8) = o;
}

__global__ __launch_bounds__(512, 2)
void gate_fusion_mfma(const float* __restrict__ xd,
                      const float* __restrict__ xc,
                      const float* __restrict__ gma,
                      const float* __restrict__ bta,
                      const float* __restrict__ Wg2,
                      const short* __restrict__ wf,
                      float* __restrict__ out, int N) {
  __shared__ short wlds[NFRAG * 512];    // 61440 B: ALL 60 weight frags
  __shared__ float tr[8][4][136];        // 17408 B: padded transpose scratch

  const int tid  = threadIdx.x;
  const int lane = tid & 63;
  const int wv   = tid >> 6;                 // 0..7
  const int r0   = blockIdx.x * 128 + wv * 16;   // 16 rows per wave
  const int cidx = lane & 15;
  const int kb   = lane >> 4;
  const bool active = (r0 < N);              // wave-uniform (N % 16 == 0)

  // ---- x loads (coalesced 64B/4-lane segments, r14 k-map)
  f32x4 buf[5][2];
  if (active) {
    const size_t row = (size_t)(r0 + cidx);
    const float* rd = xd + row * CD + kb * 4;
    const float* rc = xc + row * CC + kb * 4;
    #pragma unroll
    for (int ks = 0; ks < 5; ++ks) {
      const float* p = (ks < 2) ? (rd + ks * 32) : (rc + (ks - 2) * 32);
      buf[ks][0] = *reinterpret_cast<const f32x4*>(p);
      buf[ks][1] = *reinterpret_cast<const f32x4*>(p + 16);
    }
  }

  // ---- stage all 60 weight frags (61440 B) into LDS
  {
    #pragma unroll
    for (int it = 0; it < 8; ++it) {
      const int c = tid + it * 512;
      if (it < 7 || c < WCH_ALL) {
        short8 v = *reinterpret_cast<const short8*>(wf + (size_t)c * 8);
        *reinterpret_cast<short8*>(&wlds[c * 8]) = v;
      }
    }
  }

  __syncthreads();
  if (!active) return;   // after the only barrier

  // per-wave constants (cache-hit loads)
  float gmv[4], btv[4], w2v[4];
  #pragma unroll
  for (int nt = 0; nt < 4; ++nt) {
    const int c = nt * 16 + cidx;
    gmv[nt] = gma[c]; btv[nt] = bta[c]; w2v[nt] = Wg2[c];
  }

  // ---- convert x to bf16 A-fragments
  short8 xf[5];
  #pragma unroll
  for (int ks = 0; ks < 5; ++ks) {
    short8 f;
    #pragma unroll
    for (int j = 0; j < 4; ++j) {
      f[j]     = bf16_of(buf[ks][0][j]);
      f[4 + j] = bf16_of(buf[ks][1][j]);
    }
    xf[ks] = f;
  }

  // ---- phase 1: h = x @ Wg1  [16 x 64]  (B-frags from LDS)
  const f32x4 vzero = {0.f, 0.f, 0.f, 0.f};
  f32x4 acc1[4];
  #pragma unroll
  for (int nt = 0; nt < 4; ++nt) acc1[nt] = vzero;

  #pragma unroll
  for (int ks = 0; ks < 5; ++ks) {
    short8 bg[4];
    #pragma unroll
    for (int nt = 0; nt < 4; ++nt)
      bg[nt] = *reinterpret_cast<const short8*>(
          &wlds[(ks * 4 + nt) * 512 + lane * 8]);
    #pragma unroll
    for (int nt = 0; nt < 4; ++nt)
      acc1[nt] = __builtin_amdgcn_mfma_f32_16x16x32_bf16(
          xf[ks], bg[nt], acc1[nt], 0, 0, 0);
  }

  // ---- LayerNorm + relu + dot(Wg2) + sigmoid (C-fragment layout)
  float gate[4];
  {
    float s[4], q[4];
    #pragma unroll
    for (int r = 0; r < 4; ++r) {
      s[r] = 0.f; q[r] = 0.f;
      #pragma unroll
      for (int nt = 0; nt < 4; ++nt) {
        const float c = acc1[nt][r];
        s[r] += c; q[r] += c * c;
      }
    }
    #pragma unroll
    for (int m = 1; m < 16; m <<= 1)
      #pragma unroll
      for (int r = 0; r < 4; ++r) {
        s[r] += __shfl_xor(s[r], m, 64);
        q[r] += __shfl_xor(q[r], m, 64);
      }
    float p[4];
    #pragma unroll
    for (int r = 0; r < 4; ++r) {
      const float mu  = s[r] * (1.f / CH);
      const float var = q[r] * (1.f / CH) - mu * mu;
      const float rsd = rsqrtf(var + 1e-5f);
      float pp = 0.f;
      #pragma unroll
      for (int nt = 0; nt < 4; ++nt) {
        const float h = fmaxf((acc1[nt][r] - mu) * rsd * gmv[nt] + btv[nt], 0.f);
        pp += h * w2v[nt];
      }
      p[r] = pp;
    }
    #pragma unroll
    for (int m = 1; m < 16; m <<= 1)
      #pragma unroll
      for (int r = 0; r < 4; ++r) p[r] += __shfl_xor(p[r], m, 64);
    #pragma unroll
    for (int r = 0; r < 4; ++r) gate[r] = 1.f / (1.f + expf(-p[r]));
  }

  // ---- phase 2: all 4 nt-quarter slices, blended results kept in registers
  f32x4 o[4][2];
  #pragma unroll
  for (int q = 0; q < 4; ++q) {
    f32x4 aD[2], aC[2];
    #pragma unroll
    for (int nt = 0; nt < 2; ++nt) { aD[nt] = vzero; aC[nt] = vzero; }

    #pragma unroll
    for (int ks = 0; ks < 5; ++ks) {
      short8 bg[2];
      #pragma unroll
      for (int nt = 0; nt < 2; ++nt)
        bg[nt] = *reinterpret_cast<const short8*>(
            &wlds[(NFG1 + ks * 8 + q * 2 + nt) * 512 + lane * 8]);
      if (ks < 2) {
        #pragma unroll
        for (int nt = 0; nt < 2; ++nt)
          aD[nt] = __builtin_amdgcn_mfma_f32_16x16x32_bf16(
              xf[ks], bg[nt], aD[nt], 0, 0, 0);
      } else {
        #pragma unroll
        for (int nt = 0; nt < 2; ++nt)
          aC[nt] = __builtin_amdgcn_mfma_f32_16x16x32_bf16(
              xf[ks], bg[nt], aC[nt], 0, 0, 0);
      }
    }
    #pragma unroll
    for (int nt = 0; nt < 2; ++nt)
      #pragma unroll
      for (int r = 0; r < 4; ++r)
        o[q][nt][r] = fmaf(gate[r], aD[nt][r] - aC[nt][r], aC[nt][r]);
  }

  // ---- transpose via per-wave LDS scratch + wide NT stores (512B runs)
  {
    float (*trw)[136] = tr[wv];
    #pragma unroll
    for (int r = 0; r < 4; ++r) {
      #pragma unroll
      for (int q = 0; q < 4; ++q)
        #pragma unroll
        for (int nt = 0; nt < 2; ++nt)
          trw[kb][(q * 2 + nt) * 16 + cidx] = o[q][nt][r];
      #pragma unroll
      for (int i = 0; i < 2; ++i) {
        const int ri = i * 2 + (lane >> 5);          // scratch row 0..3
        const f32x4 v = *reinterpret_cast<const f32x4*>(
            &trw[ri][(lane & 31) * 4]);
        float* dst = &out[((size_t)r0 + ri * 4 + r) * CF + (lane & 31) * 4];
        asm volatile("global_store_dwordx4 %0, %1, off nt"
                     :: "v"(dst), "v"(v) : "memory");
      }
    }
  }
}

}  // namespace

extern "C" void kernel_launch(void* const* d_in, const int* in_sizes, int n_in,
                              void* d_out, int out_size, void* d_ws, size_t ws_size,
                              hipStream_t stream) {
  const float* xd  = (const float*)d_in[0];
  const float* xc  = (const float*)d_in[1];
  const float* Wd  = (const float*)d_in[2];
  const float* Wc  = (const float*)d_in[3];
  const float* Wg1 = (const float*)d_in[4];
  const float* gma = (const float*)d_in[5];
  const float* bta = (const float*)d_in[6];
  const float* Wg2 = (const float*)d_in[7];
  float* out = (float*)d_out;
  short* ws  = (short*)d_ws;   // needs 60 KB

  const int N = in_sizes[0] / CD;

  convert_weights<<<dim3(15), dim3(256), 0, stream>>>(Wd, Wc, Wg1, ws);

  const int nblk = (N + 127) / 128;   // 128 rows per 8-wave block
  gate_fusion_mfma<<<dim3(nblk), dim3(512), 0, stream>>>(
      xd, xc, gma, bta, Wg2, ws, out, N);
}